// Round 8
// baseline (1406.996 us; speedup 1.0000x reference)
//
#include <hip/hip_runtime.h>
#include <hip/hip_bf16.h>
#include <math.h>

#define BATCH   8
#define SEQ     1024
#define DMODEL  256
#define NHEADS  8
#define HDIM    256
#define NQKV    2048      /* NHEADS*HDIM */
#define DFF     1024
#define MROWS   (BATCH*SEQ)
#define LN_EPS  1e-3f
#define ATT_SCALE 0.0625f /* 1/sqrt(256) */

typedef unsigned int  uint;
typedef unsigned short ushort;
typedef __attribute__((ext_vector_type(8))) __bf16 bf16x8;
typedef __attribute__((ext_vector_type(4))) float   f32x4;
typedef __attribute__((ext_vector_type(4))) ushort  ushort4v;

__device__ __forceinline__ float b2f(ushort h) {
    union { uint u; float f; } v; v.u = ((uint)h) << 16; return v.f;
}
__device__ __forceinline__ ushort f2b(float f) {
    union { float f; uint u; } v; v.f = f;
    return (ushort)((v.u + 0x7FFFu + ((v.u >> 16) & 1u)) >> 16);
}
__device__ __forceinline__ uint pk2(float a, float b) {
    return (uint)f2b(a) | ((uint)f2b(b) << 16);
}

// ---------------------------------------------------------------------------
// bf16 MFMA GEMM: C[M,128-block] = A[M,K](bf16) @ Bt[N,K](bf16)^T + epilogue.
// EPI: 0 = +bias, 1 = +bias+ReLU, 2 = +bias+resid(fp32). OUTBF: 1 = bf16 C.
// 128x128 tile, BK=64, 4 waves each owning a 64x64 quadrant (4x4 of 16x16).
// LDS tiles XOR-swizzled (byte ^ ((row&7)<<4)): slot-uniform b128 access.
template<int EPI, int OUTBF>
__global__ __launch_bounds__(256, 2)
void gemm_bf16(const ushort* __restrict__ A, const ushort* __restrict__ Bt,
               const float* __restrict__ bias, const float* __restrict__ resid,
               void* __restrict__ Cv, int K, int lda, int ldc)
{
    __shared__ ushort As[128 * 64];
    __shared__ ushort Bs[128 * 64];
    const int t  = threadIdx.x;
    const int l  = t & 63;
    const int w  = t >> 6;
    const int wm = w >> 1, wn = w & 1;
    const int m0 = blockIdx.y * 128, n0 = blockIdx.x * 128;
    const int lg = l >> 4, lr = l & 15;

    f32x4 acc[4][4];
    #pragma unroll
    for (int i = 0; i < 4; i++)
        #pragma unroll
        for (int j = 0; j < 4; j++)
            acc[i][j] = (f32x4){0.f, 0.f, 0.f, 0.f};

    for (int k0 = 0; k0 < K; k0 += 64) {
        uint4 av[4], bv[4];
        #pragma unroll
        for (int j = 0; j < 4; j++) {
            const int chunk = t + j * 256;          // 0..1023
            const int row   = chunk >> 3;           // 0..127
            const int ce    = (chunk & 7) * 8;      // element col
            av[j] = *(const uint4*)&A [(size_t)(m0 + row) * lda + k0 + ce];
            bv[j] = *(const uint4*)&Bt[(size_t)(n0 + row) * K   + k0 + ce];
        }
        __syncthreads();   // previous iteration's reads done
        #pragma unroll
        for (int j = 0; j < 4; j++) {
            const int chunk = t + j * 256;
            const int row   = chunk >> 3;
            const int woff  = (chunk * 16) ^ ((row & 7) << 4);
            *(uint4*)((char*)As + woff) = av[j];
            *(uint4*)((char*)Bs + woff) = bv[j];
        }
        __syncthreads();   // tiles visible
        #pragma unroll
        for (int c = 0; c < 2; c++) {
            bf16x8 af[4], bf[4];
            #pragma unroll
            for (int i = 0; i < 4; i++) {
                const int rowA = wm * 64 + i * 16 + lr;
                const int offA = (rowA * 128 + c * 64 + lg * 16) ^ ((rowA & 7) << 4);
                af[i] = *(const bf16x8*)((const char*)As + offA);
                const int rowB = wn * 64 + i * 16 + lr;
                const int offB = (rowB * 128 + c * 64 + lg * 16) ^ ((rowB & 7) << 4);
                bf[i] = *(const bf16x8*)((const char*)Bs + offB);
            }
            #pragma unroll
            for (int mi = 0; mi < 4; mi++)
                #pragma unroll
                for (int ni = 0; ni < 4; ni++)
                    acc[mi][ni] = __builtin_amdgcn_mfma_f32_16x16x32_bf16(
                        af[mi], bf[ni], acc[mi][ni], 0, 0, 0);
        }
    }

    // epilogue: C row = m0 + wm*64 + mi*16 + lg*4 + r ; col = n0 + wn*64 + ni*16 + lr
    #pragma unroll
    for (int ni = 0; ni < 4; ni++) {
        const int col = n0 + wn * 64 + ni * 16 + lr;
        const float bb = bias[col];
        #pragma unroll
        for (int mi = 0; mi < 4; mi++) {
            #pragma unroll
            for (int r = 0; r < 4; r++) {
                const int row = m0 + wm * 64 + mi * 16 + lg * 4 + r;
                float v = acc[mi][ni][r] + bb;
                if (EPI == 1) v = fmaxf(v, 0.f);
                if (EPI == 2) v += resid[(size_t)row * ldc + col];
                if (OUTBF) ((ushort*)Cv)[(size_t)row * ldc + col] = f2b(v);
                else       ((float*) Cv)[(size_t)row * ldc + col] = v;
            }
        }
    }
}

// ---------------------------------------------------------------------------
// V transpose: V[b,s, h*256+d] (bf16) -> Vt[(b*8+h)*256 + d][s] (bf16).
// 64x64 tiles through LDS; coalesced on both sides.
__global__ __launch_bounds__(256)
void vtrans(const ushort* __restrict__ V, ushort* __restrict__ Vt)
{
    __shared__ ushort tl[64][72];
    const int s0 = blockIdx.x * 64;
    const int d0 = blockIdx.y * 64;
    const int bh = blockIdx.z;
    const int b  = bh >> 3, h = bh & 7;
    const int t  = threadIdx.x;
    #pragma unroll
    for (int j = 0; j < 2; j++) {
        const int chunk = t + j * 256;
        const int row = chunk >> 3, c8 = (chunk & 7) * 8;
        *(uint4*)&tl[row][c8] =
            *(const uint4*)&V[((size_t)(b * SEQ + s0 + row)) * NQKV + h * HDIM + d0 + c8];
    }
    __syncthreads();
    #pragma unroll
    for (int j = 0; j < 2; j++) {
        const int chunk = t + j * 256;
        const int dr = chunk >> 3, s8 = (chunk & 7) * 8;
        ushort tmp[8] __attribute__((aligned(16)));
        #pragma unroll
        for (int i = 0; i < 8; i++) tmp[i] = tl[s8 + i][dr];
        *(uint4*)&Vt[((size_t)(bh * HDIM + d0 + dr)) * SEQ + s0 + s8] = *(const uint4*)tmp;
    }
}

// ---------------------------------------------------------------------------
// MFMA flash attention v3: bf16 in/out, fp32 softmax state.
// Q,K,O: [B,S,NHEADS*HDIM] bf16. Vt: [(b*8+h)*256 + d][s] bf16.
// Block = (b,h) x 64 q-rows; 4 waves, each owns 16 q-rows.
// v3 changes vs v2 (which measured MfmaUtil 7.9%, both pipes idle):
//  - double-buffered K/V LDS -> ONE __syncthreads per tile (was 2)
//  - T13 defer-max: lane-local __all(pmax <= m+8) check; common case has
//    ZERO cross-lane shfls, no oacc rescale, no corr exp (P bounded by e^8)
//  - l kept as per-lane partial, 16-lane reduced once in epilogue
//  - s_setprio(1) around MFMA clusters (T5)
template<bool CAUSAL>
__global__ __launch_bounds__(256, 1)
void attn_mfma(const ushort* __restrict__ Q, const ushort* __restrict__ K,
               const ushort* __restrict__ Vt, ushort* __restrict__ O)
{
    // LDS: [0,16K) Kbuf0 | [16K,32K) Kbuf1 | [32K,48K) Vbuf0 | [48K,64K) Vbuf1
    //      [64K,64K+5K) P per wave ([16 q][80B], stride 40 ushorts)
    // Q staged once into [0,32K) (both K buffers) before the main loop.
    __shared__ __align__(16) char lds[70656];

    const int t  = threadIdx.x;
    const int w  = t >> 6, l = t & 63;
    const int lg = l >> 4, lr = l & 15;
    // XCD-chunked bijective swizzle over the 1024-block grid (1024 % 8 == 0)
    const int orig = blockIdx.x + (blockIdx.y << 4) + (blockIdx.z << 7);
    const int lin  = ((orig & 7) << 7) + (orig >> 3);
    const int qt0  = (lin & 15) << 6;
    const int h    = (lin >> 4) & 7;
    const int b    = lin >> 7;

    // ---- stage Q (64 rows x 512B) into [0,32K) ----
    const size_t qgbase = ((size_t)(b * SEQ + qt0)) * NQKV + (size_t)h * HDIM;
    #pragma unroll
    for (int j = 0; j < 8; j++) {
        const int chunk = t + j * 256;
        const int row = chunk >> 5, slot = chunk & 31;
        const uint4 v = *(const uint4*)&Q[qgbase + (size_t)row * NQKV + slot * 8];
        *(uint4*)(lds + row * 512 + ((slot * 16) ^ ((row & 7) << 4))) = v;
    }

    const size_t kgbase = (size_t)b * SEQ * NQKV + (size_t)h * HDIM;
    const size_t vgbase = ((size_t)(b * NHEADS + h)) * HDIM * SEQ;
    const int ntiles = CAUSAL ? (qt0 / 32 + 2) : (SEQ / 32);

    // per-thread staging offsets (constant across tiles)
    int kwoff[4], vwoff[4];
    size_t kgoff[4], vgoff[4];
    #pragma unroll
    for (int j = 0; j < 4; j++) {
        const int chunk = t + j * 256;
        const int krow = chunk >> 5, kslot = chunk & 31;
        kwoff[j] = krow * 512 + ((kslot * 16) ^ ((krow & 7) << 4));
        kgoff[j] = (size_t)krow * NQKV + kslot * 8;
        const int vrow = chunk >> 2, vslot = chunk & 3;
        vwoff[j] = vrow * 64 + ((vslot * 16) ^ ((vrow & 3) << 4));
        vgoff[j] = (size_t)vrow * SEQ + vslot * 8;
    }

    // ---- load tile 0 into regs ----
    uint4 kv[4], vv[4];
    #pragma unroll
    for (int j = 0; j < 4; j++) {
        kv[j] = *(const uint4*)&K[kgbase + kgoff[j]];
        vv[j] = *(const uint4*)&Vt[vgbase + vgoff[j]];
    }

    __syncthreads();   // Q tile visible
    bf16x8 qa[8];
    {
        const int qrow = w * 16 + lr;
        const int sw = (qrow & 7) << 4;
        #pragma unroll
        for (int ks = 0; ks < 8; ks++)
            qa[ks] = *(const bf16x8*)(lds + qrow * 512 + ((lg * 16 + ks * 64) ^ sw));
    }
    __syncthreads();   // all waves' qa reads done before buf0 overwrite

    // ---- write tile 0 -> buf0, issue tile 1 loads ----
    #pragma unroll
    for (int j = 0; j < 4; j++) {
        *(uint4*)(lds + kwoff[j])         = kv[j];
        *(uint4*)(lds + 32768 + vwoff[j]) = vv[j];
    }
    if (ntiles > 1) {
        #pragma unroll
        for (int j = 0; j < 4; j++) {
            kv[j] = *(const uint4*)&K[kgbase + (size_t)32 * NQKV + kgoff[j]];
            vv[j] = *(const uint4*)&Vt[vgbase + 32 + vgoff[j]];
        }
    }
    __syncthreads();   // buf0 visible

    f32x4 oacc[16];
    #pragma unroll
    for (int i = 0; i < 16; i++) oacc[i] = (f32x4){0.f, 0.f, 0.f, 0.f};
    float m_[4], l_[4];
    #pragma unroll
    for (int r = 0; r < 4; r++) { m_[r] = -INFINITY; l_[r] = 0.f; }

    ushort* Pw = (ushort*)(lds + 65536 + w * 1280);
    int curoff = 0;

    for (int tile = 0; tile < ntiles; tile++) {
        const int s0 = tile * 32;

        // ---- S = Q K^T (2 s-tiles x 8 k-steps) from buf[cur] ----
        f32x4 sacc[2];
        sacc[0] = (f32x4){0.f, 0.f, 0.f, 0.f};
        sacc[1] = (f32x4){0.f, 0.f, 0.f, 0.f};
        __builtin_amdgcn_s_setprio(1);
        #pragma unroll
        for (int ks = 0; ks < 8; ks++) {
            #pragma unroll
            for (int st = 0; st < 2; st++) {
                const int srow = st * 16 + lr;
                const bf16x8 kb = *(const bf16x8*)(lds + curoff + srow * 512 +
                                   ((lg * 16 + ks * 64) ^ ((srow & 7) << 4)));
                sacc[st] = __builtin_amdgcn_mfma_f32_16x16x32_bf16(qa[ks], kb, sacc[st], 0, 0, 0);
            }
        }
        __builtin_amdgcn_s_setprio(0);

        // ---- online softmax, defer-max (T13) ----
        const bool maskq = CAUSAL && (s0 + 31 > qt0 + w * 16);
        float p0s[4], p1s[4];
        bool ok = true;
        #pragma unroll
        for (int r = 0; r < 4; r++) {
            float p0 = sacc[0][r] * ATT_SCALE;
            float p1 = sacc[1][r] * ATT_SCALE;
            if (maskq) {
                const int qg = qt0 + w * 16 + lg * 4 + r;
                if (s0 + lr > qg)      p0 = -1e9f;
                if (s0 + 16 + lr > qg) p1 = -1e9f;
            }
            p0s[r] = p0; p1s[r] = p1;
            ok &= (fmaxf(p0, p1) <= m_[r] + 8.f);
        }
        if (__all((int)ok)) {
            // common case: keep stale max, no rescale, no shfl
            #pragma unroll
            for (int r = 0; r < 4; r++) {
                const float e0 = __expf(p0s[r] - m_[r]);
                const float e1 = __expf(p1s[r] - m_[r]);
                l_[r] += e0 + e1;
                Pw[(lg * 4 + r) * 40 + lr]      = f2b(e0);
                Pw[(lg * 4 + r) * 40 + 16 + lr] = f2b(e1);
            }
        } else {
            float corr[4];
            #pragma unroll
            for (int r = 0; r < 4; r++) {
                float mx = fmaxf(p0s[r], p1s[r]);
                mx = fmaxf(mx, __shfl_xor(mx, 1));
                mx = fmaxf(mx, __shfl_xor(mx, 2));
                mx = fmaxf(mx, __shfl_xor(mx, 4));
                mx = fmaxf(mx, __shfl_xor(mx, 8));
                const float newm = fmaxf(m_[r], mx);
                corr[r] = __expf(m_[r] - newm);
                m_[r] = newm;
                const float e0 = __expf(p0s[r] - newm);
                const float e1 = __expf(p1s[r] - newm);
                l_[r] = l_[r] * corr[r] + e0 + e1;
                Pw[(lg * 4 + r) * 40 + lr]      = f2b(e0);
                Pw[(lg * 4 + r) * 40 + 16 + lr] = f2b(e1);
            }
            #pragma unroll
            for (int dt = 0; dt < 16; dt++) {
                oacc[dt][0] *= corr[0]; oacc[dt][1] *= corr[1];
                oacc[dt][2] *= corr[2]; oacc[dt][3] *= corr[3];
            }
        }

        // ---- O += P V (A-frag from P LDS, B-frags from Vt buf[cur]) ----
        const bf16x8 pa = *(const bf16x8*)((const char*)Pw + lr * 80 + lg * 16);
        __builtin_amdgcn_s_setprio(1);
        #pragma unroll
        for (int dt = 0; dt < 16; dt++) {
            const int vrow = dt * 16 + lr;
            const bf16x8 vb = *(const bf16x8*)(lds + 32768 + curoff + vrow * 64 +
                               ((lg * 16) ^ ((vrow & 3) << 4)));
            oacc[dt] = __builtin_amdgcn_mfma_f32_16x16x32_bf16(pa, vb, oacc[dt], 0, 0, 0);
        }
        __builtin_amdgcn_s_setprio(0);

        // ---- stage tile t+1 into buf[cur^1]; issue loads for t+2 ----
        if (tile + 1 < ntiles) {
            const int noff = curoff ^ 16384;
            #pragma unroll
            for (int j = 0; j < 4; j++) {
                *(uint4*)(lds + noff + kwoff[j])         = kv[j];
                *(uint4*)(lds + 32768 + noff + vwoff[j]) = vv[j];
            }
            if (tile + 2 < ntiles) {
                const int s0n = s0 + 64;
                #pragma unroll
                for (int j = 0; j < 4; j++) {
                    kv[j] = *(const uint4*)&K[kgbase + (size_t)s0n * NQKV + kgoff[j]];
                    vv[j] = *(const uint4*)&Vt[vgbase + s0n + vgoff[j]];
                }
            }
        }
        __syncthreads();   // staged tile visible; buf[cur] reads drained
        curoff ^= 16384;
    }

    // ---- epilogue: reduce per-lane l partials across the 16-lane group ----
    float inv[4];
    #pragma unroll
    for (int r = 0; r < 4; r++) {
        float ls = l_[r];
        ls += __shfl_xor(ls, 1);
        ls += __shfl_xor(ls, 2);
        ls += __shfl_xor(ls, 4);
        ls += __shfl_xor(ls, 8);
        inv[r] = 1.f / ls;
    }
    const size_t obase = ((size_t)(b * SEQ + qt0 + w * 16)) * NQKV + (size_t)h * HDIM;
    #pragma unroll
    for (int dt = 0; dt < 16; dt++) {
        #pragma unroll
        for (int r = 0; r < 4; r++) {
            O[obase + (size_t)(lg * 4 + r) * NQKV + dt * 16 + lr] =
                f2b(oacc[dt][r] * inv[r]);
        }
    }
}

// ---------------------------------------------------------------------------
// LayerNorm over last dim (256). One wave per row, 4 rows per block.
// Optional bf16 dual write (Yb may be null).
__global__ __launch_bounds__(256)
void ln_f32(const float* __restrict__ X, const float* __restrict__ gamma,
            const float* __restrict__ beta, float* __restrict__ Y,
            ushort* __restrict__ Yb)
{
    const int lane = threadIdx.x & 63;
    const int row  = blockIdx.x * 4 + (threadIdx.x >> 6);
    const float4 v = *(const float4*)&X[(size_t)row * DMODEL + lane * 4];
    float s = v.x + v.y + v.z + v.w;
    #pragma unroll
    for (int o = 1; o < 64; o <<= 1) s += __shfl_xor(s, o);
    const float mu = s * (1.f / 256.f);
    const float dx = v.x - mu, dy = v.y - mu, dz = v.z - mu, dw = v.w - mu;
    float ss = dx*dx + dy*dy + dz*dz + dw*dw;
    #pragma unroll
    for (int o = 1; o < 64; o <<= 1) ss += __shfl_xor(ss, o);
    const float rstd = rsqrtf(ss * (1.f / 256.f) + LN_EPS);
    const float4 gv = *(const float4*)&gamma[lane * 4];
    const float4 bv = *(const float4*)&beta[lane * 4];
    float4 out;
    out.x = dx * rstd * gv.x + bv.x;
    out.y = dy * rstd * gv.y + bv.y;
    out.z = dz * rstd * gv.z + bv.z;
    out.w = dw * rstd * gv.w + bv.w;
    *(float4*)&Y[(size_t)row * DMODEL + lane * 4] = out;
    if (Yb) {
        uint2 p; p.x = pk2(out.x, out.y); p.y = pk2(out.z, out.w);
        *(uint2*)&Yb[(size_t)row * DMODEL + lane * 4] = p;
    }
}

// ---------------------------------------------------------------------------
// Elementwise fp32 -> bf16 cast (n8 = elements/8).
__global__ __launch_bounds__(256)
void cast_f2b(const float* __restrict__ X, ushort* __restrict__ Y, int n8)
{
    const int i = blockIdx.x * 256 + threadIdx.x;
    if (i < n8) {
        const float4 a = *(const float4*)&X[(size_t)i * 8];
        const float4 b = *(const float4*)&X[(size_t)i * 8 + 4];
        uint4 o;
        o.x = pk2(a.x, a.y); o.y = pk2(a.z, a.w);
        o.z = pk2(b.x, b.y); o.w = pk2(b.z, b.w);
        *(uint4*)&Y[(size_t)i * 8] = o;
    }
}

// Transpose-cast: W[K][N] fp32 -> Wt[N][K] bf16. Grid (N/32, K/32), block 256.
__global__ __launch_bounds__(256)
void castT_f2b(const float* __restrict__ W, ushort* __restrict__ Wt, int Kd, int Nd)
{
    __shared__ float tile[32][33];
    const int k0 = blockIdx.y * 32, n0 = blockIdx.x * 32;
    const int r  = threadIdx.x >> 3;
    const int c4 = (threadIdx.x & 7) * 4;
    const float4 v = *(const float4*)&W[(size_t)(k0 + r) * Nd + n0 + c4];
    tile[r][c4+0] = v.x; tile[r][c4+1] = v.y; tile[r][c4+2] = v.z; tile[r][c4+3] = v.w;
    __syncthreads();
    ushort4v ov = { f2b(tile[c4+0][r]), f2b(tile[c4+1][r]),
                    f2b(tile[c4+2][r]), f2b(tile[c4+3][r]) };
    *(ushort4v*)&Wt[(size_t)(n0 + r) * Kd + k0 + c4] = ov;
}

// ---------------------------------------------------------------------------
extern "C" void kernel_launch(void* const* d_in, const int* in_sizes, int n_in,
                              void* d_out, int out_size, void* d_ws, size_t ws_size,
                              hipStream_t stream)
{
    const float* x    = (const float*)d_in[0];
    const float* ctx  = (const float*)d_in[1];
    const float* Wq1  = (const float*)d_in[2];
    const float* bq1  = (const float*)d_in[3];
    const float* Wk1  = (const float*)d_in[4];
    const float* bk1  = (const float*)d_in[5];
    const float* Wv1  = (const float*)d_in[6];
    const float* bv1  = (const float*)d_in[7];
    const float* Wo1  = (const float*)d_in[8];
    const float* bo1  = (const float*)d_in[9];
    const float* g1   = (const float*)d_in[10];
    const float* be1  = (const float*)d_in[11];
    const float* Wq2  = (const float*)d_in[12];
    const float* bq2  = (const float*)d_in[13];
    const float* Wk2  = (const float*)d_in[14];
    const float* bk2  = (const float*)d_in[15];
    const float* Wv2  = (const float*)d_in[16];
    const float* bv2  = (const float*)d_in[17];
    const float* Wo2  = (const float*)d_in[18];
    const float* bo2  = (const float*)d_in[19];
    const float* g2   = (const float*)d_in[20];
    const float* be2  = (const float*)d_in[21];
    const float* W1   = (const float*)d_in[22];
    const float* b1   = (const float*)d_in[23];
    const float* W2   = (const float*)d_in[24];
    const float* b2   = (const float*)d_in[25];
    const float* g3   = (const float*)d_in[26];
    const float* be3  = (const float*)d_in[27];
    (void)in_sizes; (void)n_in; (void)out_size; (void)ws_size;

    char* base = (char*)d_ws;
    const size_t MB1 = 1024 * 1024;
    ushort* Qb   = (ushort*)(base + 0 * MB1);     // 32 MiB (O aliases)
    ushort* Kb   = (ushort*)(base + 32 * MB1);    // 32 MiB
    ushort* Vb   = (ushort*)(base + 64 * MB1);    // 32 MiB
    float*  Yf   = (float*) (base + 96 * MB1);    // 8 MiB
    float*  X1f  = (float*) (base + 104 * MB1);   // 8 MiB
    float*  X2f  = (float*) (base + 112 * MB1);   // 8 MiB
    ushort* xb   = (ushort*)(base + 120 * MB1);   // 4 MiB
    ushort* ctxb = (ushort*)(base + 124 * MB1);   // 4 MiB
    ushort* X1b  = (ushort*)(base + 128 * MB1);   // 4 MiB
    ushort* X2b  = (ushort*)(base + 132 * MB1);   // 4 MiB
    ushort* wq1t = (ushort*)(base + 136 * MB1);   // 1 MiB each
    ushort* wk1t = (ushort*)(base + 137 * MB1);
    ushort* wv1t = (ushort*)(base + 138 * MB1);
    ushort* wo1t = (ushort*)(base + 139 * MB1);
    ushort* wq2t = (ushort*)(base + 140 * MB1);
    ushort* wk2t = (ushort*)(base + 141 * MB1);
    ushort* wv2t = (ushort*)(base + 142 * MB1);
    ushort* wo2t = (ushort*)(base + 143 * MB1);
    ushort* w1t  = (ushort*)(base + 144 * MB1);   // 0.5 MiB
    ushort* w2t  = (ushort*)(base + 144 * MB1 + 512 * 1024);
    ushort* Hb   = (ushort*)(base + 145 * MB1);   // 16 MiB (ends 161)
    ushort* Vtg  = (ushort*)(base + 161 * MB1);   // 32 MiB (ends 193)

    const dim3 blk(256);
    const dim3 gQKV(NQKV/128, MROWS/128);   // (16,64)
    const dim3 gOut(DMODEL/128, MROWS/128); // (2,64)
    const dim3 gF1(DFF/128, MROWS/128);     // (8,64)
    const dim3 gAttn(SEQ/64, NHEADS, BATCH);
    const dim3 gVT(SEQ/64, HDIM/64, BATCH*NHEADS);
    const dim3 gLN(MROWS/4);

    // ---- casts ----
    cast_f2b<<<dim3((MROWS*DMODEL/8 + 255)/256), blk, 0, stream>>>(x,   xb,   MROWS*DMODEL/8);
    cast_f2b<<<dim3((MROWS*DMODEL/8 + 255)/256), blk, 0, stream>>>(ctx, ctxb, MROWS*DMODEL/8);
    castT_f2b<<<dim3(NQKV/32, DMODEL/32), blk, 0, stream>>>(Wq1, wq1t, DMODEL, NQKV);
    castT_f2b<<<dim3(NQKV/32, DMODEL/32), blk, 0, stream>>>(Wk1, wk1t, DMODEL, NQKV);
    castT_f2b<<<dim3(NQKV/32, DMODEL/32), blk, 0, stream>>>(Wv1, wv1t, DMODEL, NQKV);
    castT_f2b<<<dim3(DMODEL/32, NQKV/32), blk, 0, stream>>>(Wo1, wo1t, NQKV, DMODEL);
    castT_f2b<<<dim3(NQKV/32, DMODEL/32), blk, 0, stream>>>(Wq2, wq2t, DMODEL, NQKV);
    castT_f2b<<<dim3(NQKV/32, DMODEL/32), blk, 0, stream>>>(Wk2, wk2t, DMODEL, NQKV);
    castT_f2b<<<dim3(NQKV/32, DMODEL/32), blk, 0, stream>>>(Wv2, wv2t, DMODEL, NQKV);
    castT_f2b<<<dim3(DMODEL/32, NQKV/32), blk, 0, stream>>>(Wo2, wo2t, NQKV, DMODEL);
    castT_f2b<<<dim3(DFF/32, DMODEL/32), blk, 0, stream>>>(W1, w1t, DMODEL, DFF);
    castT_f2b<<<dim3(DMODEL/32, DFF/32), blk, 0, stream>>>(W2, w2t, DFF, DMODEL);

    // ---- causal self-attention + add&norm ----
    gemm_bf16<0,1><<<gQKV, blk, 0, stream>>>(xb, wq1t, bq1, nullptr, Qb, DMODEL, DMODEL, NQKV);
    gemm_bf16<0,1><<<gQKV, blk, 0, stream>>>(xb, wk1t, bk1, nullptr, Kb, DMODEL, DMODEL, NQKV);
    gemm_bf16<0,1><<<gQKV, blk, 0, stream>>>(xb, wv1t, bv1, nullptr, Vb, DMODEL, DMODEL, NQKV);
    vtrans<<<gVT, blk, 0, stream>>>(Vb, Vtg);
    attn_mfma<true><<<gAttn, blk, 0, stream>>>(Qb, Kb, Vtg, Qb);
    gemm_bf16<2,0><<<gOut, blk, 0, stream>>>(Qb, wo1t, bo1, x, Yf, NQKV, NQKV, DMODEL);
    ln_f32<<<gLN, blk, 0, stream>>>(Yf, g1, be1, X1f, X1b);
    // ---- cross-attention + add&norm ----
    gemm_bf16<0,1><<<gQKV, blk, 0, stream>>>(X1b,  wq2t, bq2, nullptr, Qb, DMODEL, DMODEL, NQKV);
    gemm_bf16<0,1><<<gQKV, blk, 0, stream>>>(ctxb, wk2t, bk2, nullptr, Kb, DMODEL, DMODEL, NQKV);
    gemm_bf16<0,1><<<gQKV, blk, 0, stream>>>(ctxb, wv2t, bv2, nullptr, Vb, DMODEL, DMODEL, NQKV);
    vtrans<<<gVT, blk, 0, stream>>>(Vb, Vtg);
    attn_mfma<false><<<gAttn, blk, 0, stream>>>(Qb, Kb, Vtg, Qb);
    gemm_bf16<2,0><<<gOut, blk, 0, stream>>>(Qb, wo2t, bo2, X1f, Yf, NQKV, NQKV, DMODEL);
    ln_f32<<<gLN, blk, 0, stream>>>(Yf, g2, be2, X2f, X2b);
    // ---- FFN + add&norm ----
    gemm_bf16<1,1><<<gF1,  blk, 0, stream>>>(X2b, w1t, b1, nullptr, Hb, DMODEL, DMODEL, DFF);
    gemm_bf16<2,0><<<gOut, blk, 0, stream>>>(Hb, w2t, b2, X2f, Yf, DFF, DFF, DMODEL);
    ln_f32<<<gLN, blk, 0, stream>>>(Yf, g3, be3, (float*)d_out, nullptr);
}